// Round 5
// baseline (125.225 us; speedup 1.0000x reference)
//
#include <hip/hip_runtime.h>
#include <cfloat>

// VectorQuantizer: inputs [65536,64] f32, embeddings [2048,64] f32
#define N_TOTAL 65536
#define DIM     64
#define NEMB    2048

typedef __attribute__((ext_vector_type(8))) _Float16 half8;   // MFMA A/B frag (4 VGPRs)
typedef __attribute__((ext_vector_type(4))) float    floatx4; // MFMA C/D frag

// ---------------------------------------------------------------------------
// Prep: pack embeddings as f16 in MFMA-B frag-major layout
//   chunk c = (g*2 + ks)*64 + lane, lane = q*16 + n:
//   ehp[c] = e_f16[col = g*16+n][k = ks*32 + q*8 .. +8)
// One 16-col sub = 2 chunks = 2 KB contiguous. Also fp32 norms -> en[2048].
// ---------------------------------------------------------------------------
__global__ void prep_kernel(const float* __restrict__ emb,
                            half8* __restrict__ ehp, float* __restrict__ en) {
    const int t = blockIdx.x * 256 + threadIdx.x;   // 16384 threads
    {
        const int l   = t & 63;
        const int ks  = (t >> 6) & 1;
        const int g   = t >> 7;
        const int col = g * 16 + (l & 15);
        const int kb  = ks * 32 + (l >> 4) * 8;
        const float* s = emb + col * DIM + kb;
        float4 v0 = *(const float4*)s, v1 = *(const float4*)(s + 4);
        half8 hv;
        hv[0] = (_Float16)v0.x; hv[1] = (_Float16)v0.y;
        hv[2] = (_Float16)v0.z; hv[3] = (_Float16)v0.w;
        hv[4] = (_Float16)v1.x; hv[5] = (_Float16)v1.y;
        hv[6] = (_Float16)v1.z; hv[7] = (_Float16)v1.w;
        ehp[t] = hv;
    }
    if (t < NEMB * 4) {
        const int row = t >> 2, seg = t & 3;
        const float* s = emb + row * DIM + seg * 16;
        float acc = 0.f;
#pragma unroll
        for (int i = 0; i < 4; ++i) {
            float4 v = ((const float4*)s)[i];
            acc = fmaf(v.x, v.x, acc); acc = fmaf(v.y, v.y, acc);
            acc = fmaf(v.z, v.z, acc); acc = fmaf(v.w, v.w, acc);
        }
        acc += __shfl_xor(acc, 1, 64);
        acc += __shfl_xor(acc, 2, 64);
        if (seg == 0) en[row] = acc;
    }
}

// ---------------------------------------------------------------------------
// Main — TLP round done right (R3 retry without the spill):
// Block = 4 waves, 32 rows. Wave pair p owns 16 rows (ONE row-tile: ah/al
// halved to 16 VGPRs, one accumulator, best/sec[4]); half h scans cols
// [h*1024, +1024) in 64 subs of 16 cols. 2-sub ping-pong register prefetch
// (sbuf[2][2], 16 VGPRs), immediate top-2 update (deferral was null in R2,
// saves 8 regs). Per-wave live ~55-60 VGPRs -> fits launch_bounds(256,8):
// grid 2048 blocks = 8 blocks/CU = 8 waves/SIMD (was grid-limited at 4).
//   approx q = x.eh - ||e||^2/2 + 128 (f16 2-limb x, 1-limb e)
//   packed key = (bits(q) & ~63) | (63-L); 3-op top-2 update
//     (v_and_or_b32 / v_max_u32 / v_med3_u32).
//   Epilogue: exact fp32 rescore of 4 candidates (top-2 per half).
// ---------------------------------------------------------------------------
__global__ __launch_bounds__(256, 8) void vq_mfma_kernel(
        const float* __restrict__ x, const float* __restrict__ emb,
        const char* __restrict__ ehb, const float* __restrict__ eng,
        float* __restrict__ quant, float* __restrict__ idxf,
        float* __restrict__ flat) {

    __shared__ uint4 Mrg[2][32];         // 1 KB: per-half top-2 candidates

    const int t    = threadIdx.x;
    const int wave = t >> 6, lane = t & 63;
    const int n = lane & 15, q = lane >> 4;
    const int h = wave & 1, p = wave >> 1;
    const int blk0 = blockIdx.x * 32;
    const int row0 = blk0 + p * 16;

    // ---- flat_inputs copy (block-coalesced, fire-and-forget stores) ----
    {
        const float4* s4 = (const float4*)(x + (size_t)blk0 * DIM);
        float4*       d4 = (float4*)(flat + (size_t)blk0 * DIM);
#pragma unroll
        for (int i = 0; i < 2; ++i) d4[i * 256 + t] = s4[i * 256 + t];
    }

    // ---- A fragments, f16 2-limb split. A[m=lane&15][k=q*8+j] ----
    half8 ah[2], al[2];
#pragma unroll
    for (int ks = 0; ks < 2; ++ks) {
        const float* pp = x + (size_t)(row0 + n) * DIM + ks * 32 + q * 8;
        float4 v0 = *(const float4*)pp, v1 = *(const float4*)(pp + 4);
        float xv[8] = {v0.x, v0.y, v0.z, v0.w, v1.x, v1.y, v1.z, v1.w};
#pragma unroll
        for (int j = 0; j < 8; ++j) {
            _Float16 hh = (_Float16)xv[j];
            ah[ks][j] = hh;
            al[ks][j] = (_Float16)(xv[j] - (float)hh);
        }
    }

    // key-pack mask pinned in a VGPR: v_and_or_b32 then needs only the
    // uniform Lp as its one SGPR operand -> 1 instr per element.
    unsigned maskv;
    asm("v_mov_b32 %0, 0xFFFFFFC0" : "=v"(maskv));

    unsigned best[4], sec[4];
#pragma unroll
    for (int r = 0; r < 4; ++r) { best[r] = 0u; sec[r] = 0u; }

    // per-lane stream base: sub i = 2 KB at ebase + i*2048, lane*16 within
    const char*  ebase = ehb + (size_t)h * 131072 + (size_t)lane * 16;
    const float* enp   = eng + h * 1024 + n;   // norms direct from L2

    half8 sbuf[2][2];
    float enc[2];
    // ---- prologue: subs 0,1 into buffers 0,1 ----
#pragma unroll
    for (int j = 0; j < 2; ++j) {
        const char* src = ebase + (size_t)j * 2048;
        sbuf[j][0] = *(const half8*)(src);
        sbuf[j][1] = *(const half8*)(src + 1024);
        enc[j]     = enp[j * 16];
    }

#pragma unroll 2
    for (int i = 0; i < 64; ++i) {
        const int buf = i & 1;          // static under unroll 2

        const float enh = fmaf(-0.5f, enc[buf], 128.0f);
        floatx4 e4 = {enh, enh, enh, enh};
        __builtin_amdgcn_s_setprio(1);
        floatx4 a0 = __builtin_amdgcn_mfma_f32_16x16x32_f16(ah[0], sbuf[buf][0], e4, 0, 0, 0);
        a0 = __builtin_amdgcn_mfma_f32_16x16x32_f16(al[0], sbuf[buf][0], a0, 0, 0, 0);
        a0 = __builtin_amdgcn_mfma_f32_16x16x32_f16(ah[1], sbuf[buf][1], a0, 0, 0, 0);
        a0 = __builtin_amdgcn_mfma_f32_16x16x32_f16(al[1], sbuf[buf][1], a0, 0, 0, 0);
        __builtin_amdgcn_s_setprio(0);

        // refill the just-consumed buffer with sub i+2 (WAR resolved by
        // in-order issue; compiler inserts the counted vmcnt)
        if (i < 62) {
            const char* src = ebase + (size_t)(i + 2) * 2048;
            sbuf[buf][0] = *(const half8*)(src);
            sbuf[buf][1] = *(const half8*)(src + 1024);
            enc[buf]     = enp[(i + 2) * 16];
        }

        const unsigned Lp = (unsigned)(63 - i);
#pragma unroll
        for (int r = 0; r < 4; ++r) {
            unsigned key = (__float_as_uint(a0[r]) & maskv) | Lp;  // v_and_or_b32
            unsigned nb  = best[r] > key ? best[r] : key;          // v_max_u32
            unsigned ns;
            // invariant best>=sec: new sec == median(best, sec, key)
            asm("v_med3_u32 %0, %1, %2, %3"
                : "=v"(ns) : "v"(best[r]), "v"(sec[r]), "v"(key));
            sec[r]  = ns;
            best[r] = nb;
        }
    }

    // ---- decode per-lane top-2 to (bucketed bits, full col) ----
    unsigned bval[4], bcol[4], sval[4], scol[4];
#pragma unroll
    for (int r = 0; r < 4; ++r) {
        bval[r] = best[r] & 0xFFFFFFC0u;
        bcol[r] = (unsigned)(h * 1024 + (63 - (int)(best[r] & 63u)) * 16 + n);
        sval[r] = sec[r] & 0xFFFFFFC0u;
        scol[r] = (unsigned)(h * 1024 + (63 - (int)(sec[r] & 63u)) * 16 + n);
    }
    // ---- butterfly top-2 merge across the 16 n-lanes of each q-group ----
#pragma unroll
    for (int m = 1; m < 16; m <<= 1) {
#pragma unroll
        for (int r = 0; r < 4; ++r) {
            unsigned ov  = (unsigned)__shfl_xor((int)bval[r], m, 64);
            unsigned oc  = (unsigned)__shfl_xor((int)bcol[r], m, 64);
            unsigned ov2 = (unsigned)__shfl_xor((int)sval[r], m, 64);
            unsigned oc2 = (unsigned)__shfl_xor((int)scol[r], m, 64);
            bool ow = (ov > bval[r]) || (ov == bval[r] && oc < bcol[r]);
            unsigned nbv = ow ? ov : bval[r], nbc = ow ? oc : bcol[r];
            unsigned lv  = ow ? bval[r] : ov, lc  = ow ? bcol[r] : oc;
            bool sv2 = (ov2 > sval[r]) || (ov2 == sval[r] && oc2 < scol[r]);
            unsigned bsv = sv2 ? ov2 : sval[r], bsc = sv2 ? oc2 : scol[r];
            bool s3 = (lv > bsv) || (lv == bsv && lc < bsc);
            sval[r] = s3 ? lv : bsv; scol[r] = s3 ? lc : bsc;
            bval[r] = nbv; bcol[r] = nbc;
        }
    }
    // ---- publish per-half candidates (rows: p*16 + q*4 + r) ----
    if (n == 0) {
#pragma unroll
        for (int r = 0; r < 4; ++r) {
            const int lr = p * 16 + q * 4 + r;
            Mrg[h][lr] = make_uint4(bval[r], bcol[r], sval[r], scol[r]);
        }
    }
    __syncthreads();

    // ---- exact fp32 rescore of 4 candidates; wave handles 8 rows,
    //      each 16-lane q-group owns 2 rows ----
#pragma unroll
    for (int rr = 0; rr < 2; ++rr) {
        const int lr   = wave * 8 + q * 2 + rr;
        const int grow = blk0 + lr;
        uint4 c0v = Mrg[0][lr], c1v = Mrg[1][lr];
        int cand[4] = {(int)c0v.y, (int)c0v.w, (int)c1v.y, (int)c1v.w};
        float4 xv = *(const float4*)(x + (size_t)grow * DIM + n * 4);
        float pbest = -FLT_MAX; int cbest = 0;
        float4 ebest = {0.f, 0.f, 0.f, 0.f};
#pragma unroll
        for (int c = 0; c < 4; ++c) {
            float4 e = *(const float4*)(emb + (size_t)cand[c] * DIM + n * 4);
            float pp = (xv.x - 0.5f * e.x) * e.x + (xv.y - 0.5f * e.y) * e.y
                     + (xv.z - 0.5f * e.z) * e.z + (xv.w - 0.5f * e.w) * e.w;
#pragma unroll
            for (int m2 = 1; m2 < 16; m2 <<= 1) pp += __shfl_xor(pp, m2, 64);
            bool take = (pp > pbest) || (pp == pbest && cand[c] < cbest);
            pbest = take ? pp : pbest;
            cbest = take ? cand[c] : cbest;
            ebest.x = take ? e.x : ebest.x; ebest.y = take ? e.y : ebest.y;
            ebest.z = take ? e.z : ebest.z; ebest.w = take ? e.w : ebest.w;
        }
        *(float4*)(quant + (size_t)grow * DIM + n * 4) = ebest;
        if (n == 0) idxf[grow] = (float)cbest;
    }
}

extern "C" void kernel_launch(void* const* d_in, const int* in_sizes, int n_in,
                              void* d_out, int out_size, void* d_ws, size_t ws_size,
                              hipStream_t stream) {
    const float* x   = (const float*)d_in[0];   // [65536, 64]
    const float* emb = (const float*)d_in[1];   // [2048, 64]
    float* out   = (float*)d_out;
    float* quant = out;                               // 4194304 floats
    float* idxf  = out + (size_t)N_TOTAL * DIM;       // 65536 floats
    float* flat  = idxf + N_TOTAL;                    // 4194304 floats

    half8* ehp = (half8*)d_ws;                        // 2048*64 f16 frag-major (256 KB)
    float* en  = (float*)((char*)d_ws + (size_t)NEMB * DIM * 2);  // 2048 f32

    prep_kernel<<<64, 256, 0, stream>>>(emb, ehp, en);
    vq_mfma_kernel<<<N_TOTAL / 32, 256, 0, stream>>>(x, emb, (const char*)ehp, en,
                                                     quant, idxf, flat);
}

// Round 6
// 112.458 us; speedup vs baseline: 1.1135x; 1.1135x over previous
//
#include <hip/hip_runtime.h>
#include <cfloat>

// VectorQuantizer: inputs [65536,64] f32, embeddings [2048,64] f32
#define N_TOTAL 65536
#define DIM     64
#define NEMB    2048

typedef __attribute__((ext_vector_type(8))) _Float16 half8;   // MFMA A/B frag (4 VGPRs)
typedef __attribute__((ext_vector_type(4))) float    floatx4; // MFMA C/D frag

// ---------------------------------------------------------------------------
// Prep: pack embeddings as f16 in MFMA-B frag-major layout
//   chunk c = (g*2 + ks)*64 + lane, lane = q*16 + n:
//   ehp[c] = e_f16[col = g*16+n][k = ks*32 + q*8 .. +8)
// One 16-col sub = 2 chunks = 2 KB contiguous. Also fp32 norms -> en[2048].
// ---------------------------------------------------------------------------
__global__ void prep_kernel(const float* __restrict__ emb,
                            half8* __restrict__ ehp, float* __restrict__ en) {
    const int t = blockIdx.x * 256 + threadIdx.x;   // 16384 threads
    {
        const int l   = t & 63;
        const int ks  = (t >> 6) & 1;
        const int g   = t >> 7;
        const int col = g * 16 + (l & 15);
        const int kb  = ks * 32 + (l >> 4) * 8;
        const float* s = emb + col * DIM + kb;
        float4 v0 = *(const float4*)s, v1 = *(const float4*)(s + 4);
        half8 hv;
        hv[0] = (_Float16)v0.x; hv[1] = (_Float16)v0.y;
        hv[2] = (_Float16)v0.z; hv[3] = (_Float16)v0.w;
        hv[4] = (_Float16)v1.x; hv[5] = (_Float16)v1.y;
        hv[6] = (_Float16)v1.z; hv[7] = (_Float16)v1.w;
        ehp[t] = hv;
    }
    if (t < NEMB * 4) {
        const int row = t >> 2, seg = t & 3;
        const float* s = emb + row * DIM + seg * 16;
        float acc = 0.f;
#pragma unroll
        for (int i = 0; i < 4; ++i) {
            float4 v = ((const float4*)s)[i];
            acc = fmaf(v.x, v.x, acc); acc = fmaf(v.y, v.y, acc);
            acc = fmaf(v.z, v.z, acc); acc = fmaf(v.w, v.w, acc);
        }
        acc += __shfl_xor(acc, 1, 64);
        acc += __shfl_xor(acc, 2, 64);
        if (seg == 0) en[row] = acc;
    }
}

// ---------------------------------------------------------------------------
// Main (R4 geometry: 64 rows/block, 1024 blocks, bounds(256,4) — R5's
// 32-row split regressed via doubled per-block overhead; R3's 8-wave cap
// spilled).
// Block = 4 waves. Wave pair p owns 32 rows; half h scans cols
// [h*1024, +1024) in 64 subs of 16 cols. Sub-granular register prefetch,
// distance 3 (sbuf[4][2]); zero barriers / LDS in the K-loop.
//   THIS ROUND: SINGLE-limb f16 (dropped the low-limb pass). MFMA per sub
//   8 -> 4, accumulator chains 4-deep -> 2-deep, prologue conversion
//   halved, 16 VGPRs freed. Rationale: the exact fp32 rescore of 4
//   candidates absorbs the extra approx error (single-limb dot error
//   ~2-4e-3 << typical inter-candidate distance gaps); the approx pass
//   only has to land the true argmin in the top-2-per-half.
//   approx q = x_f16 . e_f16 - ||e||^2/2 + 128
//   packed key = (bits(q) & ~63) | (63-L); 3-op top-2 update
//     (v_and_or_b32 / v_max_u32 / v_med3_u32), deferred one sub.
//   Epilogue: exact fp32 rescore of 4 candidates (top-2 per half).
// ---------------------------------------------------------------------------
__global__ __launch_bounds__(256, 4) void vq_mfma_kernel(
        const float* __restrict__ x, const float* __restrict__ emb,
        const char* __restrict__ ehb, const float* __restrict__ eng,
        float* __restrict__ quant, float* __restrict__ idxf,
        float* __restrict__ flat) {

    __shared__ uint4 Mrg[2][64];         // 2 KB: per-half top-2 candidates

    const int t    = threadIdx.x;
    const int wave = t >> 6, lane = t & 63;
    const int n = lane & 15, q = lane >> 4;
    const int h = wave & 1, p = wave >> 1;
    const int blk0 = blockIdx.x * 64;
    const int row0 = blk0 + p * 32;

    // ---- flat_inputs copy (block-coalesced, fire-and-forget stores) ----
    {
        const float4* s4 = (const float4*)(x + (size_t)blk0 * DIM);
        float4*       d4 = (float4*)(flat + (size_t)blk0 * DIM);
#pragma unroll
        for (int i = 0; i < 4; ++i) d4[i * 256 + t] = s4[i * 256 + t];
    }

    // ---- A fragments, f16 single-limb. A[m=lane&15][k=q*8+j] ----
    half8 ah[2][2];
#pragma unroll
    for (int tl = 0; tl < 2; ++tl)
#pragma unroll
        for (int ks = 0; ks < 2; ++ks) {
            const float* pp = x + (size_t)(row0 + tl * 16 + n) * DIM + ks * 32 + q * 8;
            float4 v0 = *(const float4*)pp, v1 = *(const float4*)(pp + 4);
            float xv[8] = {v0.x, v0.y, v0.z, v0.w, v1.x, v1.y, v1.z, v1.w};
#pragma unroll
            for (int j = 0; j < 8; ++j)
                ah[tl][ks][j] = (_Float16)xv[j];
        }

    // key-pack mask pinned in a VGPR: v_and_or_b32 then needs only the
    // uniform Lp as its one SGPR operand -> 1 instr per element.
    unsigned maskv;
    asm("v_mov_b32 %0, 0xFFFFFFC0" : "=v"(maskv));

    unsigned best[8], sec[8];
#pragma unroll
    for (int r = 0; r < 8; ++r) { best[r] = 0u; sec[r] = 0u; }

    // per-lane stream base: sub i = 2 KB at ebase + i*2048, lane*16 within
    const char*  ebase = ehb + (size_t)h * 131072 + (size_t)lane * 16;
    const float* enp   = eng + h * 1024 + n;   // norms direct from L2

    half8 sbuf[4][2];
    float encp[4];
    // ---- prologue: subs 0..2 into buffers 0..2 ----
#pragma unroll
    for (int j = 0; j < 3; ++j) {
        const char* src = ebase + (size_t)j * 2048;
        sbuf[j][0] = *(const half8*)(src);
        sbuf[j][1] = *(const half8*)(src + 1024);
        encp[j]    = enp[j * 16];
    }

    // pipelined state: previous sub's accumulators + its packed L tag.
    floatx4 qa0 = {0.f, 0.f, 0.f, 0.f};
    floatx4 qa1 = {0.f, 0.f, 0.f, 0.f};
    unsigned qLp = 0u;

#pragma unroll 4
    for (int i = 0; i < 64; ++i) {
        const int buf = i & 3;          // static under unroll 4
        if (i < 61) {                   // uniform scalar guard; index static
            const int pb = (i + 3) & 3;
            const char* src = ebase + (size_t)(i + 3) * 2048;
            sbuf[pb][0] = *(const half8*)(src);
            sbuf[pb][1] = *(const half8*)(src + 1024);
            encp[pb]    = enp[(i + 3) * 16];
        }

        const float enh = fmaf(-0.5f, encp[buf], 128.0f);
        floatx4 e4 = {enh, enh, enh, enh};
        half8 bk0 = sbuf[buf][0];
        half8 bk1 = sbuf[buf][1];
        __builtin_amdgcn_s_setprio(1);
        floatx4 a0 = __builtin_amdgcn_mfma_f32_16x16x32_f16(ah[0][0], bk0, e4, 0, 0, 0);
        floatx4 a1 = __builtin_amdgcn_mfma_f32_16x16x32_f16(ah[1][0], bk0, e4, 0, 0, 0);
        a0 = __builtin_amdgcn_mfma_f32_16x16x32_f16(ah[0][1], bk1, a0, 0, 0, 0);
        a1 = __builtin_amdgcn_mfma_f32_16x16x32_f16(ah[1][1], bk1, a1, 0, 0, 0);
        __builtin_amdgcn_s_setprio(0);

        // ---- deferred top-2 update: previous sub's results (qa*, qLp) ----
#pragma unroll
        for (int r = 0; r < 8; ++r) {
            float v = (r < 4) ? qa0[r] : qa1[r - 4];
            unsigned key = (__float_as_uint(v) & maskv) | qLp;  // v_and_or_b32
            unsigned nb  = best[r] > key ? best[r] : key;       // v_max_u32
            unsigned ns;
            // invariant best>=sec: new sec == median(best, sec, key)
            asm("v_med3_u32 %0, %1, %2, %3"
                : "=v"(ns) : "v"(best[r]), "v"(sec[r]), "v"(key));
            sec[r]  = ns;
            best[r] = nb;
        }
        qa0 = a0; qa1 = a1;
        qLp = (unsigned)(63 - i);
    }

    // ---- drain: last sub's results ----
#pragma unroll
    for (int r = 0; r < 8; ++r) {
        float v = (r < 4) ? qa0[r] : qa1[r - 4];
        unsigned key = (__float_as_uint(v) & maskv) | qLp;
        unsigned nb  = best[r] > key ? best[r] : key;
        unsigned ns;
        asm("v_med3_u32 %0, %1, %2, %3"
            : "=v"(ns) : "v"(best[r]), "v"(sec[r]), "v"(key));
        sec[r]  = ns;
        best[r] = nb;
    }

    // ---- decode per-lane top-2 to (bucketed bits, full col) ----
    unsigned bval[8], bcol[8], sval[8], scol[8];
#pragma unroll
    for (int r = 0; r < 8; ++r) {
        bval[r] = best[r] & 0xFFFFFFC0u;
        bcol[r] = (unsigned)(h * 1024 + (63 - (int)(best[r] & 63u)) * 16 + n);
        sval[r] = sec[r] & 0xFFFFFFC0u;
        scol[r] = (unsigned)(h * 1024 + (63 - (int)(sec[r] & 63u)) * 16 + n);
    }
    // ---- butterfly top-2 merge across the 16 n-lanes of each q-group ----
#pragma unroll
    for (int m = 1; m < 16; m <<= 1) {
#pragma unroll
        for (int r = 0; r < 8; ++r) {
            unsigned ov  = (unsigned)__shfl_xor((int)bval[r], m, 64);
            unsigned oc  = (unsigned)__shfl_xor((int)bcol[r], m, 64);
            unsigned ov2 = (unsigned)__shfl_xor((int)sval[r], m, 64);
            unsigned oc2 = (unsigned)__shfl_xor((int)scol[r], m, 64);
            bool ow = (ov > bval[r]) || (ov == bval[r] && oc < bcol[r]);
            unsigned nbv = ow ? ov : bval[r], nbc = ow ? oc : bcol[r];
            unsigned lv  = ow ? bval[r] : ov, lc  = ow ? bcol[r] : oc;
            bool sv2 = (ov2 > sval[r]) || (ov2 == sval[r] && oc2 < scol[r]);
            unsigned bsv = sv2 ? ov2 : sval[r], bsc = sv2 ? oc2 : scol[r];
            bool s3 = (lv > bsv) || (lv == bsv && lc < bsc);
            sval[r] = s3 ? lv : bsv; scol[r] = s3 ? lc : bsc;
            bval[r] = nbv; bcol[r] = nbc;
        }
    }
    // ---- publish per-half candidates (rows: tl*16 + q*4 + r) ----
    if (n == 0) {
#pragma unroll
        for (int r = 0; r < 8; ++r) {
            const int lr = p * 32 + (r >> 2) * 16 + q * 4 + (r & 3);
            Mrg[h][lr] = make_uint4(bval[r], bcol[r], sval[r], scol[r]);
        }
    }
    __syncthreads();

    // ---- exact fp32 rescore of 4 candidates; wave w handles 16 rows ----
#pragma unroll
    for (int r = 0; r < 4; ++r) {
        const int lr   = wave * 16 + q * 4 + r;
        const int grow = blk0 + lr;
        uint4 c0v = Mrg[0][lr], c1v = Mrg[1][lr];
        int cand[4] = {(int)c0v.y, (int)c0v.w, (int)c1v.y, (int)c1v.w};
        float4 xv = *(const float4*)(x + (size_t)grow * DIM + n * 4);
        float pbest = -FLT_MAX; int cbest = 0;
        float4 ebest = {0.f, 0.f, 0.f, 0.f};
#pragma unroll
        for (int c = 0; c < 4; ++c) {
            float4 e = *(const float4*)(emb + (size_t)cand[c] * DIM + n * 4);
            float pp = (xv.x - 0.5f * e.x) * e.x + (xv.y - 0.5f * e.y) * e.y
                     + (xv.z - 0.5f * e.z) * e.z + (xv.w - 0.5f * e.w) * e.w;
#pragma unroll
            for (int m2 = 1; m2 < 16; m2 <<= 1) pp += __shfl_xor(pp, m2, 64);
            bool take = (pp > pbest) || (pp == pbest && cand[c] < cbest);
            pbest = take ? pp : pbest;
            cbest = take ? cand[c] : cbest;
            ebest.x = take ? e.x : ebest.x; ebest.y = take ? e.y : ebest.y;
            ebest.z = take ? e.z : ebest.z; ebest.w = take ? e.w : ebest.w;
        }
        *(float4*)(quant + (size_t)grow * DIM + n * 4) = ebest;
        if (n == 0) idxf[grow] = (float)cbest;
    }
}

extern "C" void kernel_launch(void* const* d_in, const int* in_sizes, int n_in,
                              void* d_out, int out_size, void* d_ws, size_t ws_size,
                              hipStream_t stream) {
    const float* x   = (const float*)d_in[0];   // [65536, 64]
    const float* emb = (const float*)d_in[1];   // [2048, 64]
    float* out   = (float*)d_out;
    float* quant = out;                               // 4194304 floats
    float* idxf  = out + (size_t)N_TOTAL * DIM;       // 65536 floats
    float* flat  = idxf + N_TOTAL;                    // 4194304 floats

    half8* ehp = (half8*)d_ws;                        // 2048*64 f16 frag-major (256 KB)
    float* en  = (float*)((char*)d_ws + (size_t)NEMB * DIM * 2);  // 2048 f32

    prep_kernel<<<64, 256, 0, stream>>>(emb, ehp, en);
    vq_mfma_kernel<<<N_TOTAL / 64, 256, 0, stream>>>(x, emb, (const char*)ehp, en,
                                                     quant, idxf, flat);
}